// Round 1
// baseline (77.756 us; speedup 1.0000x reference)
//
#include <hip/hip_runtime.h>

// Problem constants (from reference): B=32, T=256, D=128, tau=0.02
#define B_SZ 32
#define T_SZ 256
#define D_SZ 128
#define TAU_INV 50.0f

typedef __bf16 bf16x8 __attribute__((ext_vector_type(8)));
typedef float f32x4 __attribute__((ext_vector_type(4)));

__device__ __forceinline__ unsigned short f2bf(float f) {
    union { float f; unsigned int u; } v; v.f = f;
    unsigned int r = v.u + 0x7fffu + ((v.u >> 16) & 1u);  // RNE
    return (unsigned short)(r >> 16);
}

// masks arrive either as int32 (harness "integer -> int*") or raw bool bytes.
// Element [0][0] is always true (q_len,p_len >= 64), so int32 layout reads 1,
// byte layout reads 0x01010101. Deterministic (input-only) detection.
__device__ __forceinline__ bool mask_is_byte(const void* m) {
    return ((const int*)m)[0] != 1;
}
__device__ __forceinline__ int mget(const void* m, int idx, bool isb) {
    return isb ? (((const unsigned char*)m)[idx] != 0) : (((const int*)m)[idx] != 0);
}

// ---------------- Kernel A: fp32 -> bf16 conversion -------------------------
__global__ __launch_bounds__(256) void cvt_bf16(const float* __restrict__ src,
                                                unsigned short* __restrict__ dst) {
    int i = (blockIdx.x * 256 + threadIdx.x) * 4;
    float4 v = *(const float4*)(src + i);
    ushort4 o;
    o.x = f2bf(v.x); o.y = f2bf(v.y); o.z = f2bf(v.z); o.w = f2bf(v.w);
    *(ushort4*)(dst + i) = o;
}

// ---------------- Kernel B: late-interaction raw scores ---------------------
// block (b,c): simT[p][q] = sum_d P[c,p,d]*Q[b,q,d], masked max over p per q,
// masked sum over q -> sraw[b*32+c]  (division by t_i deferred to kernel C)
__global__ __launch_bounds__(256) void late_sim(
    const unsigned short* __restrict__ Qbf, const unsigned short* __restrict__ Pbf,
    const void* __restrict__ qmask, const void* __restrict__ pmask,
    float* __restrict__ sraw)
{
    __shared__ __align__(16) unsigned char Plds[T_SZ * D_SZ * 2]; // 64 KB, XOR-swizzled
    __shared__ float madd[T_SZ];  // 0 or -1e30 per p token
    __shared__ float qmul[T_SZ];  // 1 or 0 per q token
    __shared__ float wsum[4];

    const int tid = threadIdx.x;
    const int l   = tid & 63;
    const int w   = tid >> 6;       // wave 0..3
    const int bid = blockIdx.x;
    const int b   = bid >> 5;
    const int c   = bid & 31;
    const int lr  = l & 15;         // fragment row/col lane
    const int lg  = l >> 4;         // k-group / row-group

    const bool isb = mask_is_byte(qmask);
    const unsigned short* Qb = Qbf + b * (T_SZ * D_SZ);
    const unsigned short* Pc = Pbf + c * (T_SZ * D_SZ);

    // stage P tile -> LDS with chunk swizzle: chunk' = chunk ^ (row&7)
    // (row stride 256B: without swizzle ds_read_b128 across 16 rows is a
    //  same-bank pileup; with it, 2-way aliasing = free)
    #pragma unroll
    for (int it = 0; it < 16; ++it) {
        int m   = it * 256 + tid;       // 16B chunk id, coalesced across tid
        int row = m >> 4;
        int cs  = m & 15;
        bf16x8 v = *(const bf16x8*)(Pc + m * 8);
        *(bf16x8*)(Plds + row * 256 + ((cs ^ (row & 7)) << 4)) = v;
    }
    {
        madd[tid] = mget(pmask, c * T_SZ + tid, isb) ? 0.0f : -1e30f;
        qmul[tid] = mget(qmask, b * T_SZ + tid, isb) ? 1.0f : 0.0f;
    }

    // Q fragments (B operand: lane holds Q[q0+qt*16+lr][k*32+lg*8 .. +7])
    const int q0 = w * 64;
    bf16x8 qf[4][4];
    #pragma unroll
    for (int qt = 0; qt < 4; ++qt)
        #pragma unroll
        for (int k = 0; k < 4; ++k)
            qf[qt][k] = *(const bf16x8*)(Qb + (q0 + qt * 16 + lr) * D_SZ + k * 32 + lg * 8);

    __syncthreads();

    float rmax[4] = {-3e38f, -3e38f, -3e38f, -3e38f};

    for (int pt = 0; pt < 16; ++pt) {
        f32x4 acc[4];
        #pragma unroll
        for (int qt = 0; qt < 4; ++qt) acc[qt] = (f32x4){0.f, 0.f, 0.f, 0.f};
        #pragma unroll
        for (int k = 0; k < 4; ++k) {
            int row = pt * 16 + lr;
            bf16x8 af = *(const bf16x8*)(Plds + row * 256 + (((k * 4 + lg) ^ (row & 7)) << 4));
            #pragma unroll
            for (int qt = 0; qt < 4; ++qt)
                acc[qt] = __builtin_amdgcn_mfma_f32_16x16x32_bf16(af, qf[qt][k], acc[qt], 0, 0, 0);
        }
        // C layout: col(q)=lane&15, row(p)= pt*16 + (lane>>4)*4 + reg
        float pm0 = madd[pt * 16 + lg * 4 + 0];
        float pm1 = madd[pt * 16 + lg * 4 + 1];
        float pm2 = madd[pt * 16 + lg * 4 + 2];
        float pm3 = madd[pt * 16 + lg * 4 + 3];
        #pragma unroll
        for (int qt = 0; qt < 4; ++qt) {
            float m0 = fmaxf(fmaxf(acc[qt][0] + pm0, acc[qt][1] + pm1),
                             fmaxf(acc[qt][2] + pm2, acc[qt][3] + pm3));
            rmax[qt] = fmaxf(rmax[qt], m0);
        }
    }

    // combine the 4 row-groups: lanes {x,16+x,32+x,48+x} hold partial maxes
    #pragma unroll
    for (int qt = 0; qt < 4; ++qt) {
        float v = rmax[qt];
        v = fmaxf(v, __shfl_xor(v, 16));
        v = fmaxf(v, __shfl_xor(v, 32));
        rmax[qt] = v;
    }
    // masked sum over this wave's 64 q tokens (each value replicated 4x)
    float tot = 0.f;
    #pragma unroll
    for (int qt = 0; qt < 4; ++qt) tot += rmax[qt] * qmul[q0 + qt * 16 + lr];
    #pragma unroll
    for (int off = 32; off > 0; off >>= 1) tot += __shfl_down(tot, off);
    if (l == 0) wsum[w] = tot * 0.25f;
    __syncthreads();
    if (tid == 0) sraw[bid] = wsum[0] + wsum[1] + wsum[2] + wsum[3];
}

// ---------------- Kernel C: dense sim + losses ------------------------------
__global__ __launch_bounds__(256) void loss_final(
    const float* __restrict__ qs, const float* __restrict__ ps,
    const float* __restrict__ sraw, const void* __restrict__ qmask,
    float* __restrict__ out)
{
    __shared__ float qsL[B_SZ * D_SZ];
    __shared__ float psL[B_SZ * D_SZ];
    __shared__ float dense[B_SZ][B_SZ];
    __shared__ float late[B_SZ][B_SZ];
    __shared__ float tcnt[B_SZ];
    __shared__ float rs[B_SZ], rm[B_SZ], rk[B_SZ];

    const int tid = threadIdx.x;
    const bool isb = mask_is_byte(qmask);

    for (int i = tid; i < B_SZ * D_SZ; i += 256) { qsL[i] = qs[i]; psL[i] = ps[i]; }
    if (tid < B_SZ) {
        int cnt = 0;
        for (int t = 0; t < T_SZ; ++t) cnt += mget(qmask, tid * T_SZ + t, isb);
        tcnt[tid] = (float)(cnt > 1 ? cnt : 1);
    }
    __syncthreads();

    for (int idx = tid; idx < B_SZ * B_SZ; idx += 256) {
        int r = idx >> 5, cc = idx & 31;
        float s = 0.f;
        #pragma unroll
        for (int i = 0; i < D_SZ; i += 4) {
            float4 a  = *(const float4*)(qsL + r  * D_SZ + i);
            float4 bb = *(const float4*)(psL + cc * D_SZ + i);
            s += a.x * bb.x + a.y * bb.y + a.z * bb.z + a.w * bb.w;
        }
        dense[r][cc] = s;
        late[r][cc]  = sraw[idx] / tcnt[r];
    }
    __syncthreads();

    if (tid < B_SZ) {
        const int r = tid;
        float md = -3e38f, my = -3e38f;
        for (int cc = 0; cc < B_SZ; ++cc) {
            md = fmaxf(md, dense[r][cc] * TAU_INV);
            my = fmaxf(my, late[r][cc] * TAU_INV);
        }
        float sd = 0.f, sy = 0.f;
        for (int cc = 0; cc < B_SZ; ++cc) {
            sd += expf(dense[r][cc] * TAU_INV - md);
            sy += expf(late[r][cc] * TAU_INV - my);
        }
        float lsd = md + logf(sd), lsy = my + logf(sy);
        rs[r] = -(dense[r][r] * TAU_INV - lsd);
        rm[r] = -(late[r][r]  * TAU_INV - lsy);
        float kl = 0.f;
        for (int cc = 0; cc < B_SZ; ++cc) {
            float pd = expf(dense[r][cc] * TAU_INV - lsd);
            float pl = expf(late[r][cc]  * TAU_INV - lsy);
            kl += pd * logf((pd + 1e-8f) / (pl + 1e-8f));
        }
        rk[r] = kl;
    }
    __syncthreads();

    if (tid == 0) {
        float s1 = 0.f, s2 = 0.f, s3 = 0.f;
        for (int r = 0; r < B_SZ; ++r) { s1 += rs[r]; s2 += rm[r]; s3 += rk[r]; }
        s1 *= (1.0f / B_SZ); s2 *= (1.0f / B_SZ); s3 *= (1.0f / B_SZ);
        out[0] = s1 + s2 + s3;  // total
        out[1] = s1;            // single_loss
        out[2] = s2;            // multi_loss
        out[3] = s3;            // kl
    }
}

// ---------------------------------------------------------------------------
extern "C" void kernel_launch(void* const* d_in, const int* in_sizes, int n_in,
                              void* d_out, int out_size, void* d_ws, size_t ws_size,
                              hipStream_t stream) {
    const float* qs    = (const float*)d_in[0];  // query_single [32,128]
    const float* ps    = (const float*)d_in[1];  // pos_single   [32,128]
    const float* qm3   = (const float*)d_in[2];  // query_multi  [32,256,128]
    const float* pm3   = (const float*)d_in[3];  // pos_multi    [32,256,128]
    const void*  qmask = d_in[4];                // q_mask [32,256]
    const void*  pmask = d_in[5];                // p_mask [32,256]
    float* out = (float*)d_out;

    const int NTOK = B_SZ * T_SZ * D_SZ;         // 1,048,576
    unsigned short* Qbf = (unsigned short*)d_ws;
    unsigned short* Pbf = Qbf + NTOK;
    float* sraw = (float*)(Pbf + NTOK);          // [32,32]

    cvt_bf16<<<NTOK / (256 * 4), 256, 0, stream>>>(qm3, Qbf);
    cvt_bf16<<<NTOK / (256 * 4), 256, 0, stream>>>(pm3, Pbf);
    late_sim<<<B_SZ * B_SZ, 256, 0, stream>>>(Qbf, Pbf, qmask, pmask, sraw);
    loss_final<<<1, 256, 0, stream>>>(qs, ps, sraw, qmask, out);
}

// Round 2
// 45.633 us; speedup vs baseline: 1.7039x; 1.7039x over previous
//
#include <hip/hip_runtime.h>

// Problem constants (from reference): B=32, T=256, D=128, tau=0.02
#define B_SZ 32
#define T_SZ 256
#define D_SZ 128
#define TAU_INV 50.0f

typedef __bf16 bf16x8 __attribute__((ext_vector_type(8)));
typedef float f32x4 __attribute__((ext_vector_type(4)));

__device__ __forceinline__ unsigned short f2bf(float f) {
    union { float f; unsigned int u; } v; v.f = f;
    unsigned int r = v.u + 0x7fffu + ((v.u >> 16) & 1u);  // RNE
    return (unsigned short)(r >> 16);
}

// masks arrive either as int32 (harness "integer -> int*") or raw bool bytes.
// Element [0][0] is always true (q_len,p_len >= 64), so int32 layout reads 1,
// byte layout reads 0x01010101. Deterministic (input-only) detection.
__device__ __forceinline__ bool mask_is_byte(const void* m) {
    return ((const int*)m)[0] != 1;
}
__device__ __forceinline__ int mget(const void* m, int idx, bool isb) {
    return isb ? (((const unsigned char*)m)[idx] != 0) : (((const int*)m)[idx] != 0);
}

// ---------------- Kernel A: fp32 -> bf16 conversion -------------------------
__global__ __launch_bounds__(256) void cvt_bf16(const float* __restrict__ src,
                                                unsigned short* __restrict__ dst) {
    int i = (blockIdx.x * 256 + threadIdx.x) * 4;
    float4 v = *(const float4*)(src + i);
    ushort4 o;
    o.x = f2bf(v.x); o.y = f2bf(v.y); o.z = f2bf(v.z); o.w = f2bf(v.w);
    *(ushort4*)(dst + i) = o;
}

// ---------------- Kernel B: late-interaction raw scores ---------------------
// block (b,c): simT[p][q] = sum_d P[c,p,d]*Q[b,q,d], masked max over p per q,
// masked sum over q -> sraw[b*32+c]  (division by t_i deferred to kernel C)
__global__ __launch_bounds__(256) void late_sim(
    const unsigned short* __restrict__ Qbf, const unsigned short* __restrict__ Pbf,
    const void* __restrict__ qmask, const void* __restrict__ pmask,
    float* __restrict__ sraw)
{
    __shared__ __align__(16) unsigned char Plds[T_SZ * D_SZ * 2]; // 64 KB, XOR-swizzled
    __shared__ float madd[T_SZ];  // 0 or -1e30 per p token
    __shared__ float qmul[T_SZ];  // 1 or 0 per q token
    __shared__ float wsum[4];

    const int tid = threadIdx.x;
    const int l   = tid & 63;
    const int w   = tid >> 6;       // wave 0..3
    const int bid = blockIdx.x;
    const int b   = bid >> 5;
    const int c   = bid & 31;
    const int lr  = l & 15;         // fragment row/col lane
    const int lg  = l >> 4;         // k-group / row-group

    const bool isb = mask_is_byte(qmask);
    const unsigned short* Qb = Qbf + b * (T_SZ * D_SZ);
    const unsigned short* Pc = Pbf + c * (T_SZ * D_SZ);

    // stage P tile -> LDS with chunk swizzle: chunk' = chunk ^ (row&7)
    #pragma unroll
    for (int it = 0; it < 16; ++it) {
        int m   = it * 256 + tid;       // 16B chunk id, coalesced across tid
        int row = m >> 4;
        int cs  = m & 15;
        bf16x8 v = *(const bf16x8*)(Pc + m * 8);
        *(bf16x8*)(Plds + row * 256 + ((cs ^ (row & 7)) << 4)) = v;
    }
    {
        madd[tid] = mget(pmask, c * T_SZ + tid, isb) ? 0.0f : -1e30f;
        qmul[tid] = mget(qmask, b * T_SZ + tid, isb) ? 1.0f : 0.0f;
    }

    // Q fragments (B operand: lane holds Q[q0+qt*16+lr][k*32+lg*8 .. +7])
    const int q0 = w * 64;
    bf16x8 qf[4][4];
    #pragma unroll
    for (int qt = 0; qt < 4; ++qt)
        #pragma unroll
        for (int k = 0; k < 4; ++k)
            qf[qt][k] = *(const bf16x8*)(Qb + (q0 + qt * 16 + lr) * D_SZ + k * 32 + lg * 8);

    __syncthreads();

    float rmax[4] = {-3e38f, -3e38f, -3e38f, -3e38f};

    for (int pt = 0; pt < 16; ++pt) {
        f32x4 acc[4];
        #pragma unroll
        for (int qt = 0; qt < 4; ++qt) acc[qt] = (f32x4){0.f, 0.f, 0.f, 0.f};
        #pragma unroll
        for (int k = 0; k < 4; ++k) {
            int row = pt * 16 + lr;
            bf16x8 af = *(const bf16x8*)(Plds + row * 256 + (((k * 4 + lg) ^ (row & 7)) << 4));
            #pragma unroll
            for (int qt = 0; qt < 4; ++qt)
                acc[qt] = __builtin_amdgcn_mfma_f32_16x16x32_bf16(af, qf[qt][k], acc[qt], 0, 0, 0);
        }
        // C layout: col(q)=lane&15, row(p)= pt*16 + (lane>>4)*4 + reg
        float pm0 = madd[pt * 16 + lg * 4 + 0];
        float pm1 = madd[pt * 16 + lg * 4 + 1];
        float pm2 = madd[pt * 16 + lg * 4 + 2];
        float pm3 = madd[pt * 16 + lg * 4 + 3];
        #pragma unroll
        for (int qt = 0; qt < 4; ++qt) {
            float m0 = fmaxf(fmaxf(acc[qt][0] + pm0, acc[qt][1] + pm1),
                             fmaxf(acc[qt][2] + pm2, acc[qt][3] + pm3));
            rmax[qt] = fmaxf(rmax[qt], m0);
        }
    }

    // combine the 4 row-groups: lanes {x,16+x,32+x,48+x} hold partial maxes
    #pragma unroll
    for (int qt = 0; qt < 4; ++qt) {
        float v = rmax[qt];
        v = fmaxf(v, __shfl_xor(v, 16));
        v = fmaxf(v, __shfl_xor(v, 32));
        rmax[qt] = v;
    }
    // masked sum over this wave's 64 q tokens (each value replicated 4x)
    float tot = 0.f;
    #pragma unroll
    for (int qt = 0; qt < 4; ++qt) tot += rmax[qt] * qmul[q0 + qt * 16 + lr];
    #pragma unroll
    for (int off = 32; off > 0; off >>= 1) tot += __shfl_down(tot, off);
    if (l == 0) wsum[w] = tot * 0.25f;
    __syncthreads();
    if (tid == 0) sraw[bid] = wsum[0] + wsum[1] + wsum[2] + wsum[3];
}

// ---------------- Kernel C: dense sim + losses (fully parallel) -------------
__global__ __launch_bounds__(256) void loss_final(
    const float* __restrict__ qs, const float* __restrict__ ps,
    const float* __restrict__ sraw, const void* __restrict__ qmask,
    float* __restrict__ out)
{
    __shared__ float qsL[B_SZ * D_SZ];
    __shared__ float psL[B_SZ * D_SZ];
    __shared__ float dense[B_SZ][B_SZ];
    __shared__ float late[B_SZ][B_SZ];
    __shared__ float tcnt[B_SZ];
    __shared__ float rs[B_SZ], rm[B_SZ], rk[B_SZ];

    const int tid = threadIdx.x;
    const bool isb = mask_is_byte(qmask);

    // stage single vectors: 4096 floats each, float4-vectorized
    for (int i = tid * 4; i < B_SZ * D_SZ; i += 256 * 4) {
        *(float4*)(qsL + i) = *(const float4*)(qs + i);
        *(float4*)(psL + i) = *(const float4*)(ps + i);
    }

    // token counts: 8 threads per row, vectorized byte/int sums, shuffle-reduce
    {
        const int r = tid >> 3, j = tid & 7;   // row, 32-token chunk
        int cnt = 0;
        if (isb) {
            const unsigned int* mm = (const unsigned int*)((const unsigned char*)qmask + r * T_SZ + j * 32);
            #pragma unroll
            for (int t = 0; t < 8; ++t)
                cnt += (int)((mm[t] * 0x01010101u) >> 24);   // sum of 4 {0,1} bytes
        } else {
            const int* mm = (const int*)qmask + r * T_SZ + j * 32;
            #pragma unroll
            for (int t = 0; t < 32; ++t) cnt += (mm[t] != 0);
        }
        cnt += __shfl_xor(cnt, 1);
        cnt += __shfl_xor(cnt, 2);
        cnt += __shfl_xor(cnt, 4);
        if (j == 0) tcnt[r] = (float)(cnt > 1 ? cnt : 1);
    }
    __syncthreads();

    // dense sim + scaled late sim: 4 (r,c) pairs per thread
    for (int idx = tid; idx < B_SZ * B_SZ; idx += 256) {
        int r = idx >> 5, cc = idx & 31;
        float s = 0.f;
        #pragma unroll
        for (int i = 0; i < D_SZ; i += 4) {
            float4 a  = *(const float4*)(qsL + r  * D_SZ + i);
            float4 bb = *(const float4*)(psL + cc * D_SZ + i);
            s += a.x * bb.x + a.y * bb.y + a.z * bb.z + a.w * bb.w;
        }
        dense[r][cc] = s;
        late[r][cc]  = sraw[idx] / tcnt[r];
    }
    __syncthreads();

    // per-row softmax/CE/KL: 8 rows at a time, 32 lanes per row
    const int cc = tid & 31;
    #pragma unroll
    for (int it = 0; it < 4; ++it) {
        const int r = (tid >> 5) + 8 * it;
        float xd = dense[r][cc] * TAU_INV;
        float xl = late[r][cc]  * TAU_INV;
        float md = xd, ml = xl;
        #pragma unroll
        for (int off = 16; off > 0; off >>= 1) {
            md = fmaxf(md, __shfl_xor(md, off));
            ml = fmaxf(ml, __shfl_xor(ml, off));
        }
        float ed = expf(xd - md), el = expf(xl - ml);
        float sd = ed, sl = el;
        #pragma unroll
        for (int off = 16; off > 0; off >>= 1) {
            sd += __shfl_xor(sd, off);
            sl += __shfl_xor(sl, off);
        }
        float lsd = md + logf(sd);
        float lsl = ml + logf(sl);
        float pd = expf(xd - lsd);
        float pl = expf(xl - lsl);
        float klt = pd * logf((pd + 1e-8f) / (pl + 1e-8f));
        #pragma unroll
        for (int off = 16; off > 0; off >>= 1) klt += __shfl_xor(klt, off);
        if (cc == 0)  rk[r] = klt;
        if (cc == r & 31 ? (cc == (r & 31)) : true) {} // (no-op; keep structure simple)
        if (cc == r) { rs[r] = -(xd - lsd); rm[r] = -(xl - lsl); }
    }
    __syncthreads();

    if (tid < B_SZ) {
        float a = rs[tid], b = rm[tid], c = rk[tid];
        #pragma unroll
        for (int off = 16; off > 0; off >>= 1) {
            a += __shfl_xor(a, off);
            b += __shfl_xor(b, off);
            c += __shfl_xor(c, off);
        }
        if (tid == 0) {
            a *= (1.0f / B_SZ); b *= (1.0f / B_SZ); c *= (1.0f / B_SZ);
            out[0] = a + b + c;  // total
            out[1] = a;          // single_loss
            out[2] = b;          // multi_loss
            out[3] = c;          // kl
        }
    }
}

// ---------------------------------------------------------------------------
extern "C" void kernel_launch(void* const* d_in, const int* in_sizes, int n_in,
                              void* d_out, int out_size, void* d_ws, size_t ws_size,
                              hipStream_t stream) {
    const float* qs    = (const float*)d_in[0];  // query_single [32,128]
    const float* ps    = (const float*)d_in[1];  // pos_single   [32,128]
    const float* qm3   = (const float*)d_in[2];  // query_multi  [32,256,128]
    const float* pm3   = (const float*)d_in[3];  // pos_multi    [32,256,128]
    const void*  qmask = d_in[4];                // q_mask [32,256]
    const void*  pmask = d_in[5];                // p_mask [32,256]
    float* out = (float*)d_out;

    const int NTOK = B_SZ * T_SZ * D_SZ;         // 1,048,576
    unsigned short* Qbf = (unsigned short*)d_ws;
    unsigned short* Pbf = Qbf + NTOK;
    float* sraw = (float*)(Pbf + NTOK);          // [32,32]

    cvt_bf16<<<NTOK / (256 * 4), 256, 0, stream>>>(qm3, Qbf);
    cvt_bf16<<<NTOK / (256 * 4), 256, 0, stream>>>(pm3, Pbf);
    late_sim<<<B_SZ * B_SZ, 256, 0, stream>>>(Qbf, Pbf, qmask, pmask, sraw);
    loss_final<<<1, 256, 0, stream>>>(qs, ps, sraw, qmask, out);
}